// Round 9
// baseline (449.149 us; speedup 1.0000x reference)
//
#include <hip/hip_runtime.h>
#include <hip/hip_bf16.h>

// Int8Linear: out[M,N] = (x[M,K] fp32) x (w[N,K] int8-in-int32)^T * scale[N]
// Round 9: occupancy axis. 128x128 x BK=128 i8 tiles (64 KB LDS) -> 2 blocks/CU
// (cross-block overlap hides barrier/lgkm stalls; m114) and 5504 blocks
// (97.7% tail fill vs 89.6% at 1376). Schedule = r7's proven 3-barrier
// lookahead, halved read counts. Fragment/staging byte geometry per row is
// IDENTICAL to r5/r7 (128-B rows, chunk^(row&7) swizzle, measured 0 conflicts).

#define M_DIM 8192
#define N_DIM 11008
#define K_DIM 4096

#define BM 128
#define BN 128
#define BK 128   // int8 elems -> 128 B per LDS row, 32 K-tiles

using f32x4  = __attribute__((ext_vector_type(4))) float;
using i32x4  = __attribute__((ext_vector_type(4))) int;
using s16x4  = __attribute__((ext_vector_type(4))) short;
using s16x8  = __attribute__((ext_vector_type(8))) short;

typedef __attribute__((address_space(3))) void lds_void_t;
typedef __attribute__((address_space(1))) const void gbl_void_t;

__device__ __forceinline__ short cvt_bf16(float f) {
    union { float f; unsigned u; } v; v.f = f;
    unsigned r = v.u + 0x7fffu + ((v.u >> 16) & 1u);  // RNE
    return (short)(r >> 16);
}

// ---- prepass: per-row symmetric int8 quantization of x ----
__global__ __launch_bounds__(256) void quant_x(const float* __restrict__ X,
                                               signed char* __restrict__ Q,
                                               float* __restrict__ sx) {
    const int row = blockIdx.x;
    const int tid = threadIdx.x;
    const f32x4* xr = (const f32x4*)(X + (size_t)row * K_DIM);

    f32x4 v[4];
    float m = 0.f;
    #pragma unroll
    for (int i = 0; i < 4; ++i) {
        v[i] = xr[tid * 4 + i];
        #pragma unroll
        for (int j = 0; j < 4; ++j) m = fmaxf(m, fabsf(v[i][j]));
    }
    #pragma unroll
    for (int off = 32; off; off >>= 1) m = fmaxf(m, __shfl_xor(m, off));
    __shared__ float wmax[4];
    if ((tid & 63) == 0) wmax[tid >> 6] = m;
    __syncthreads();
    m = fmaxf(fmaxf(wmax[0], wmax[1]), fmaxf(wmax[2], wmax[3]));

    const float inv = (m > 0.f) ? 127.0f / m : 0.f;
    i32x4 o;
    #pragma unroll
    for (int i = 0; i < 4; ++i) {
        int b0 = __float2int_rn(v[i][0] * inv) & 255;
        int b1 = __float2int_rn(v[i][1] * inv) & 255;
        int b2 = __float2int_rn(v[i][2] * inv) & 255;
        int b3 = __float2int_rn(v[i][3] * inv) & 255;
        o[i] = b0 | (b1 << 8) | (b2 << 16) | (b3 << 24);
    }
    ((i32x4*)(Q + (size_t)row * K_DIM))[tid] = o;
    if (tid == 0) sx[row] = (m > 0.f) ? m * (1.0f / 127.0f) : 0.f;
}

// ---- prepass: int32 weights -> packed int8 (exact) ----
__global__ __launch_bounds__(256) void convert_w(const int* __restrict__ W,
                                                 signed char* __restrict__ Q, int n16) {
    int i = blockIdx.x * blockDim.x + threadIdx.x;
    const int stride = gridDim.x * blockDim.x;
    for (; i < n16; i += stride) {
        i32x4 o;
        #pragma unroll
        for (int j = 0; j < 4; ++j) {
            i32x4 v = ((const i32x4*)W)[i * 4 + j];
            o[j] = (v[0] & 255) | ((v[1] & 255) << 8) | ((v[2] & 255) << 16) | (v[3] << 24);
        }
        ((i32x4*)Q)[i] = o;
    }
}

#define SBAR __builtin_amdgcn_s_barrier()
#define LGKM(n) do { asm volatile("s_waitcnt lgkmcnt(" #n ")" ::: "memory"); \
                     __builtin_amdgcn_sched_barrier(0); } while (0)
#define WAIT_VM(n) do { asm volatile("s_waitcnt vmcnt(" #n ")" ::: "memory"); \
                        __builtin_amdgcn_sched_barrier(0); } while (0)

// Stage one operand tile (128 rows x 128 B = 16 KB): 4 gload_lds x 256 thr x 16 B.
// LDS dest LINEAR; bank swizzle via pre-swizzled global source chunk (jl).
#define STAGE(bufi, opi, srcp, T) do {                                             \
    signed char* _d = &lds[bufi][opi][0];                                          \
    const size_t _toff = (size_t)((T) & 31) * 128;                                 \
    _Pragma("unroll")                                                              \
    for (int _i = 0; _i < 4; ++_i)                                                 \
        __builtin_amdgcn_global_load_lds(                                          \
            (gbl_void_t*)((srcp) + (size_t)_i * 32 * K_DIM + _toff),               \
            (lds_void_t*)(_d + (_i * 256 + tid) * 16), 16, 0, 0);                  \
} while (0)

// Read A quadrant qm: 2 m-frags x 2 k-steps = 4 x ds_read_b128 (r5/r7 addressing,
// measured zero-conflict). byte = row*128 + ((chunk ^ (row&7))<<4), chunk=(k<<2)|fq.
#define READ_A(dst, bufi, qm) do {                                                 \
    const signed char* _s = &lds[bufi][0][0];                                      \
    _Pragma("unroll")                                                              \
    for (int _m = 0; _m < 2; ++_m)                                                 \
        _Pragma("unroll")                                                          \
        for (int _k = 0; _k < 2; ++_k)                                             \
            dst[_m][_k] = *(const i32x4*)(_s                                       \
                + (size_t)((mi * 64 + (qm) * 32 + _m * 16 + fr) * 128)             \
                + ((((_k << 2) | fq) ^ fr7) << 4));                                \
} while (0)

// Read B quadrant qn: 2 n-frags x 2 k-steps = 4 x ds_read_b128.
#define READ_B(dst, bufi, qn) do {                                                 \
    const signed char* _s = &lds[bufi][1][0];                                      \
    _Pragma("unroll")                                                              \
    for (int _n = 0; _n < 2; ++_n)                                                 \
        _Pragma("unroll")                                                          \
        for (int _k = 0; _k < 2; ++_k)                                             \
            dst[_n][_k] = *(const i32x4*)(_s                                       \
                + (size_t)((ni * 64 + (qn) * 32 + _n * 16 + fr) * 128)             \
                + ((((_k << 2) | fq) ^ fr7) << 4));                                \
} while (0)

#define MFMA_Q(qm, qn, aset, bset) do {                                            \
    __builtin_amdgcn_s_setprio(1);                                                 \
    _Pragma("unroll")                                                              \
    for (int _m = 0; _m < 2; ++_m)                                                 \
        _Pragma("unroll")                                                          \
        for (int _n = 0; _n < 2; ++_n)                                             \
            _Pragma("unroll")                                                      \
            for (int _k = 0; _k < 2; ++_k)                                         \
                acc[(qm) * 2 + _m][(qn) * 2 + _n] =                                \
                    __builtin_amdgcn_mfma_i32_16x16x64_i8(                         \
                        aset[_m][_k], bset[_n][_k],                                \
                        acc[(qm) * 2 + _m][(qn) * 2 + _n], 0, 0, 0);               \
    __builtin_amdgcn_s_setprio(0);                                                 \
} while (0)

// r7's ledger, halved counts. Tile T from BUF; OBUF holds T+1.
// LGKM: enter P1 [a0' 4, b0' 4]=8; P1 +8 -> LGKM(8) drains a0',b0'.
//   P2 q01 needs b1 -> compiler lgkm(4). P3 +4 (a0 of T+1) -> LGKM(4) drains a1.
//   P4 +4 (b0 of T+1) -> 8 = steady.
// VM: stages B(T+2)@P3, A(T+2)@P4; at P2-end in flight = B(T+1)+A(T+1) (8,
//   issued 4-6 phases prior); VM(0) drains -> OBUF reads at P3/P4 safe after bar.
// Region safety: identical structure to r7 (B staged P3 after b1@P2 drains;
//   A staged P4 after a1@P3 LGKM(4) pre-barrier; a0/b0 drained P1 LGKM(8)).
#define HALF_ITER(BUF, OBUF, B0, B0N, T) do {                                      \
    /* P1: q00 = a0 x b0 */                                                        \
    READ_B(b1, BUF, 1);                                                            \
    READ_A(a1, BUF, 1);                                                            \
    LGKM(8);                                                                       \
    MFMA_Q(0, 0, a0, B0);                                                          \
    SBAR;                                                                          \
    /* P2: q01 = a0 x b1; drain T+1 stages */                                      \
    MFMA_Q(0, 1, a0, b1);                                                          \
    WAIT_VM(0);                                                                    \
    SBAR;                                                                          \
    /* P3: q11 = a1 x b1; stage B(T+2); prefetch a0(T+1) */                        \
    STAGE(BUF, 1, Bsrc, (T) + 2);                                                  \
    READ_A(a0, OBUF, 0);                                                           \
    LGKM(4);                                                                       \
    MFMA_Q(1, 1, a1, b1);                                                          \
    SBAR;                                                                          \
    /* P4: q10 = a1 x b0; stage A(T+2); prefetch b0(T+1); no barrier */            \
    STAGE(BUF, 0, Asrc, (T) + 2);                                                  \
    READ_B(B0N, OBUF, 0);                                                          \
    MFMA_Q(1, 0, a1, B0);                                                          \
} while (0)

__global__ __launch_bounds__(256, 2) void gemm_i8(
    const signed char* __restrict__ A,   // [M, K] int8 (quantized x)
    const signed char* __restrict__ B,   // [N, K] int8 (weights)
    const float* __restrict__ sx,        // [M] row scales of x
    const float* __restrict__ scale,     // [N] channel scales of w
    float*       __restrict__ C)         // [M, N]
{
    __shared__ __align__(16) signed char lds[2][2][128 * 128];  // 64 KiB -> 2 blocks/CU

    const int tid  = threadIdx.x;
    const int lane = tid & 63;
    const int fr   = lane & 15;
    const int fq   = lane >> 4;
    const int fr7  = fr & 7;
    const int wave = tid >> 6;
    const int mi   = wave >> 1;   // 0..1: 64-row block
    const int ni   = wave & 1;    // 0..1: 64-col block

    // XCD-chunked bijective swizzle: 5504 = 8 x 688; per XCD: 8 bm x 86 bn
    // (bm fastest -> 1 MB A-stripe + streaming W per XCD, W L3-resident).
    const int bid = blockIdx.x;
    const int xcd = bid & 7;
    const int idx = bid >> 3;             // 0..687
    const int bm  = xcd * 8 + (idx & 7);  // 0..63
    const int bn  = idx >> 3;             // 0..85

    // Pre-swizzled staging source: chunk c = i*256+tid -> row = i*32+(tid>>3),
    // src chunk = (tid&7) ^ (row&7) = (tid&7) ^ ((tid>>3)&7).  (bytes)
    const int jl   = (tid & 7) ^ ((tid >> 3) & 7);
    const int soff = (tid >> 3) * K_DIM + jl * 16;
    const signed char* Asrc = A + (size_t)bm * BM * K_DIM + soff;
    const signed char* Bsrc = B + (size_t)bn * BN * K_DIM + soff;

    i32x4 acc[4][4] = {};
    i32x4 a0[2][2], a1[2][2];            // A quadrants of current tile
    i32x4 b0e[2][2], b0o[2][2], b1[2][2];// b0 rotates per tile parity

    // Prologue: stage tiles 0,1; wait tile 0 (leave tile 1's 8 in flight);
    // pre-issue a0(T0), b0(T0) -> 8 outstanding = steady state.
    STAGE(0, 1, Bsrc, 0);
    STAGE(0, 0, Asrc, 0);
    STAGE(1, 1, Bsrc, 1);
    STAGE(1, 0, Asrc, 1);
    WAIT_VM(8);
    SBAR;
    READ_A(a0, 0, 0);
    READ_B(b0e, 0, 0);

    for (int it = 0; it < 16; ++it) {
        const int t0 = 2 * it;
        HALF_ITER(0, 1, b0e, b0o, t0);      // tile t0   (buf0)
        HALF_ITER(1, 0, b0o, b0e, t0 + 1);  // tile t0+1 (buf1)
    }

    // Epilogue: per (i,jj) row, 4 consecutive jn-stores cover 256 B of the row.
    const int row0 = bm * BM + mi * 64 + fq * 4;
    const int col0 = bn * BN + ni * 64 + fr;
    float s4[4];
    #pragma unroll
    for (int jn = 0; jn < 4; ++jn) s4[jn] = scale[col0 + jn * 16];
    #pragma unroll
    for (int i = 0; i < 4; ++i) {
        #pragma unroll
        for (int jj = 0; jj < 4; ++jj) {
            const int r = row0 + i * 16 + jj;
            const float sxv = sx[r];
            #pragma unroll
            for (int jn = 0; jn < 4; ++jn)
                __builtin_nontemporal_store(
                    (float)acc[i][jn][jj] * sxv * s4[jn],
                    &C[(size_t)r * N_DIM + col0 + jn * 16]);
        }
    }
}

// ---- fallback (round-1 fused bf16 kernel) if ws is too small ----
#define FBM 128
#define FBN 128
#define FBK 32
#define LDK 40
__global__ __launch_bounds__(256) void int8_linear_fused(
    const float* __restrict__ A, const int* __restrict__ W,
    const float* __restrict__ scale, float* __restrict__ C)
{
    __shared__ short As[FBM][LDK];
    __shared__ short Bs[FBN][LDK];
    const int tid = threadIdx.x;
    const int bid = blockIdx.x;
    const int g   = bid / (8 * 86);
    const int rem = bid % (8 * 86);
    const int bm  = g * 8 + (rem & 7);
    const int bn  = rem >> 3;
    const int srow = tid >> 3;
    const int skq  = tid & 7;
    const float* Ab = A + (size_t)(bm * FBM + srow) * K_DIM + skq * 4;
    const int*   Wb = W + (size_t)(bn * FBN + srow) * K_DIM + skq * 4;
    const int lane = tid & 63, wave = tid >> 6;
    const int wm = (wave >> 1) * 64, wn = (wave & 1) * 64;
    const int fr = lane & 15, fq = lane >> 4;
    f32x4 acc[4][4] = {};
    f32x4 areg[4]; i32x4 breg[4];
    #pragma unroll
    for (int i = 0; i < 4; ++i) {
        areg[i] = *(const f32x4*)(Ab + (size_t)(i * 32) * K_DIM);
        breg[i] = *(const i32x4*)(Wb + (size_t)(i * 32) * K_DIM);
    }
    const int NT = K_DIM / FBK;
    for (int kt = 0; kt < NT; ++kt) {
        __syncthreads();
        #pragma unroll
        for (int i = 0; i < 4; ++i) {
            s16x4 av, bv;
            #pragma unroll
            for (int j = 0; j < 4; ++j) {
                av[j] = cvt_bf16(areg[i][j]);
                bv[j] = cvt_bf16((float)breg[i][j]);
            }
            *(s16x4*)&As[srow + i * 32][skq * 4] = av;
            *(s16x4*)&Bs[srow + i * 32][skq * 4] = bv;
        }
        __syncthreads();
        if (kt + 1 < NT) {
            const int k0 = (kt + 1) * FBK;
            #pragma unroll
            for (int i = 0; i < 4; ++i) {
                areg[i] = *(const f32x4*)(Ab + (size_t)(i * 32) * K_DIM + k0);
                breg[i] = *(const i32x4*)(Wb + (size_t)(i * 32) * K_DIM + k0);
            }
        }
        s16x8 af[4], bf[4];
        #pragma unroll
        for (int m = 0; m < 4; ++m) af[m] = *(const s16x8*)&As[wm + m * 16 + fr][fq * 8];
        #pragma unroll
        for (int n = 0; n < 4; ++n) bf[n] = *(const s16x8*)&Bs[wn + n * 16 + fr][fq * 8];
        #pragma unroll
        for (int m = 0; m < 4; ++m)
            #pragma unroll
            for (int n = 0; n < 4; ++n)
                acc[m][n] = __builtin_amdgcn_mfma_f32_16x16x32_bf16(af[m], bf[n], acc[m][n], 0, 0, 0);
    }
    #pragma unroll
    for (int n = 0; n < 4; ++n) {
        const int gn = bn * FBN + wn + n * 16 + fr;
        const float s = scale[gn];
        #pragma unroll
        for (int m = 0; m < 4; ++m) {
            const int gm0 = bm * FBM + wm + m * 16 + fq * 4;
            #pragma unroll
            for (int j = 0; j < 4; ++j)
                C[(size_t)(gm0 + j) * N_DIM + gn] = acc[m][n][j] * s;
        }
    }
}

extern "C" void kernel_launch(void* const* d_in, const int* in_sizes, int n_in,
                              void* d_out, int out_size, void* d_ws, size_t ws_size,
                              hipStream_t stream) {
    const float* x  = (const float*)d_in[0];
    const int*   w  = (const int*)d_in[1];
    const float* sc = (const float*)d_in[2];
    float* out = (float*)d_out;

    const size_t w_bytes  = (size_t)N_DIM * K_DIM;
    const size_t x_bytes  = (size_t)M_DIM * K_DIM;
    const size_t sx_bytes = (size_t)M_DIM * sizeof(float);
    const size_t need = w_bytes + x_bytes + sx_bytes;

    if (ws_size >= need) {
        signed char* qw = (signed char*)d_ws;
        signed char* qx = qw + w_bytes;
        float* sx = (float*)(qx + x_bytes);
        convert_w<<<dim3(2048), dim3(256), 0, stream>>>(w, qw, (int)(w_bytes / 16));
        quant_x<<<dim3(M_DIM), dim3(256), 0, stream>>>(x, qx, sx);
        const int nblocks = (M_DIM / BM) * (N_DIM / BN);  // 64 * 86 = 5504
        gemm_i8<<<dim3(nblocks), dim3(256), 0, stream>>>(qx, qw, sx, sc, out);
    } else {
        const int nblocks = (M_DIM / FBM) * (N_DIM / FBN);
        int8_linear_fused<<<dim3(nblocks), dim3(256), 0, stream>>>(x, w, sc, out);
    }
}

// Round 10
// 415.530 us; speedup vs baseline: 1.0809x; 1.0809x over previous
//
#include <hip/hip_runtime.h>
#include <hip/hip_bf16.h>

// Int8Linear: out[M,N] = (x[M,K] fp32) x (w[N,K] int8-in-int32)^T * scale[N]
// Round 10: r7 chassis (best: 402 us GEMM) + staging spread 2/2/4 across
// P2/P3/P4 (was 4/4 at P3/P4) + counted WAIT_VM(2) (never drains to 0 in-loop;
// waits only tile T+1's stages, issued 2-4 phases prior). All read ledgers,
// barrier placement (end P1/P2/P3), and region proofs unchanged from r7.

#define M_DIM 8192
#define N_DIM 11008
#define K_DIM 4096

#define BM 256
#define BN 256
#define BK 128   // int8 elems -> 128 B per LDS row, 32 K-tiles

using f32x4  = __attribute__((ext_vector_type(4))) float;
using i32x4  = __attribute__((ext_vector_type(4))) int;
using s16x4  = __attribute__((ext_vector_type(4))) short;
using s16x8  = __attribute__((ext_vector_type(8))) short;

typedef __attribute__((address_space(3))) void lds_void_t;
typedef __attribute__((address_space(1))) const void gbl_void_t;

__device__ __forceinline__ short cvt_bf16(float f) {
    union { float f; unsigned u; } v; v.f = f;
    unsigned r = v.u + 0x7fffu + ((v.u >> 16) & 1u);  // RNE
    return (short)(r >> 16);
}

// ---- prepass: per-row symmetric int8 quantization of x ----
__global__ __launch_bounds__(256) void quant_x(const float* __restrict__ X,
                                               signed char* __restrict__ Q,
                                               float* __restrict__ sx) {
    const int row = blockIdx.x;
    const int tid = threadIdx.x;
    const f32x4* xr = (const f32x4*)(X + (size_t)row * K_DIM);

    f32x4 v[4];
    float m = 0.f;
    #pragma unroll
    for (int i = 0; i < 4; ++i) {
        v[i] = xr[tid * 4 + i];
        #pragma unroll
        for (int j = 0; j < 4; ++j) m = fmaxf(m, fabsf(v[i][j]));
    }
    #pragma unroll
    for (int off = 32; off; off >>= 1) m = fmaxf(m, __shfl_xor(m, off));
    __shared__ float wmax[4];
    if ((tid & 63) == 0) wmax[tid >> 6] = m;
    __syncthreads();
    m = fmaxf(fmaxf(wmax[0], wmax[1]), fmaxf(wmax[2], wmax[3]));

    const float inv = (m > 0.f) ? 127.0f / m : 0.f;
    i32x4 o;
    #pragma unroll
    for (int i = 0; i < 4; ++i) {
        int b0 = __float2int_rn(v[i][0] * inv) & 255;
        int b1 = __float2int_rn(v[i][1] * inv) & 255;
        int b2 = __float2int_rn(v[i][2] * inv) & 255;
        int b3 = __float2int_rn(v[i][3] * inv) & 255;
        o[i] = b0 | (b1 << 8) | (b2 << 16) | (b3 << 24);
    }
    ((i32x4*)(Q + (size_t)row * K_DIM))[tid] = o;
    if (tid == 0) sx[row] = (m > 0.f) ? m * (1.0f / 127.0f) : 0.f;
}

// ---- prepass: int32 weights -> packed int8 (exact) ----
__global__ __launch_bounds__(256) void convert_w(const int* __restrict__ W,
                                                 signed char* __restrict__ Q, int n16) {
    int i = blockIdx.x * blockDim.x + threadIdx.x;
    const int stride = gridDim.x * blockDim.x;
    for (; i < n16; i += stride) {
        i32x4 o;
        #pragma unroll
        for (int j = 0; j < 4; ++j) {
            i32x4 v = ((const i32x4*)W)[i * 4 + j];
            o[j] = (v[0] & 255) | ((v[1] & 255) << 8) | ((v[2] & 255) << 16) | (v[3] << 24);
        }
        ((i32x4*)Q)[i] = o;
    }
}

#define SBAR __builtin_amdgcn_s_barrier()
#define LGKM(n) do { asm volatile("s_waitcnt lgkmcnt(" #n ")" ::: "memory"); \
                     __builtin_amdgcn_sched_barrier(0); } while (0)
#define WAIT_VM(n) do { asm volatile("s_waitcnt vmcnt(" #n ")" ::: "memory"); \
                        __builtin_amdgcn_sched_barrier(0); } while (0)

// Full-tile stage (4 gloads) and half-tile stage (2 gloads, rows h*128..+127).
#define STAGE(bufi, opi, srcp, T) do {                                             \
    signed char* _d = &lds[bufi][opi][0];                                          \
    const size_t _toff = (size_t)((T) & 31) * 128;                                 \
    _Pragma("unroll")                                                              \
    for (int _i = 0; _i < 4; ++_i)                                                 \
        __builtin_amdgcn_global_load_lds(                                          \
            (gbl_void_t*)((srcp) + (size_t)_i * 64 * K_DIM + _toff),               \
            (lds_void_t*)(_d + (_i * 512 + tid) * 16), 16, 0, 0);                  \
} while (0)

#define STAGE_H(bufi, opi, srcp, T, h) do {                                        \
    signed char* _d = &lds[bufi][opi][0];                                          \
    const size_t _toff = (size_t)((T) & 31) * 128;                                 \
    _Pragma("unroll")                                                              \
    for (int _i = 2 * (h); _i < 2 * (h) + 2; ++_i)                                 \
        __builtin_amdgcn_global_load_lds(                                          \
            (gbl_void_t*)((srcp) + (size_t)_i * 64 * K_DIM + _toff),               \
            (lds_void_t*)(_d + (_i * 512 + tid) * 16), 16, 0, 0);                  \
} while (0)

// Read A quadrant qm: 4 m-frags x 2 k-steps = 8 x ds_read_b128 (r5/r7 addressing,
// measured zero-conflict). byte = row*128 + ((chunk ^ (row&7))<<4), chunk=(k<<2)|fq.
#define READ_A(dst, bufi, qm) do {                                                 \
    const signed char* _s = &lds[bufi][0][0];                                      \
    _Pragma("unroll")                                                              \
    for (int _m = 0; _m < 4; ++_m)                                                 \
        _Pragma("unroll")                                                          \
        for (int _k = 0; _k < 2; ++_k)                                             \
            dst[_m][_k] = *(const i32x4*)(_s                                       \
                + (size_t)((mi * 128 + (qm) * 64 + _m * 16 + fr) * 128)            \
                + ((((_k << 2) | fq) ^ fr7) << 4));                                \
} while (0)

// Read B quadrant qn: 2 n-frags x 2 k-steps = 4 x ds_read_b128.
#define READ_B(dst, bufi, qn) do {                                                 \
    const signed char* _s = &lds[bufi][1][0];                                      \
    _Pragma("unroll")                                                              \
    for (int _n = 0; _n < 2; ++_n)                                                 \
        _Pragma("unroll")                                                          \
        for (int _k = 0; _k < 2; ++_k)                                             \
            dst[_n][_k] = *(const i32x4*)(_s                                       \
                + (size_t)((ni * 64 + (qn) * 32 + _n * 16 + fr) * 128)             \
                + ((((_k << 2) | fq) ^ fr7) << 4));                                \
} while (0)

#define MFMA_Q(qm, qn, aset, bset) do {                                            \
    __builtin_amdgcn_s_setprio(1);                                                 \
    _Pragma("unroll")                                                              \
    for (int _m = 0; _m < 4; ++_m)                                                 \
        _Pragma("unroll")                                                          \
        for (int _n = 0; _n < 2; ++_n)                                             \
            _Pragma("unroll")                                                      \
            for (int _k = 0; _k < 2; ++_k)                                         \
                acc[(qm) * 4 + _m][(qn) * 2 + _n] =                                \
                    __builtin_amdgcn_mfma_i32_16x16x64_i8(                         \
                        aset[_m][_k], bset[_n][_k],                                \
                        acc[(qm) * 4 + _m][(qn) * 2 + _n], 0, 0, 0);               \
    __builtin_amdgcn_s_setprio(0);                                                 \
} while (0)

// r7 ledger with staging spread 2/2/4 and counted VM(2):
// LGKM: enter P1 [a0' 8 (P3 of T-1), b0' 4 (P4 of T-1)] = 12; P1 +12 ->
//   LGKM(12) drains a0',b0'.  P2 q01 needs b1 -> compiler counted wait (~1
//   phase old).  P3 +8 (a0 of T+1) -> LGKM(8) drains a1 (2 phases old).
//   P4 +4 (b0 of T+1) -> 12 = steady.
// VM (stages: Bh0(T+2)@P2, Bh1(T+2)@P3, A(T+2)@P4): entering P2(T) formal
//   outstanding = [Bh0(T+1)@P2(T-1) 2, Bh1(T+1)@P3(T-1) 2, A(T+1)@P4(T-1) 4,
//   Bh0(T+2)@P2(T) 2].  WAIT_VM(2) waits until <=2 remain -> drains all of
//   T+1 (2-4 phases old, cheap), leaves the same-phase Bh0(T+2) in flight.
//   T+1 then fully in LDS before the end-P2 barrier -> P3/P4 OBUF reads safe.
// Regions: Bh0/Bh1(T+2) write BUF.B after end-P1/end-P2 barriers; BUF.B's
//   reads (b1@P1 via LGKM(12) pre-end-P1, b0@P4(T-1) likewise) are drained
//   before end-P1. A(T+2)@P4 after end-P3 barrier; BUF.A reads a1@P1 drained
//   by LGKM(8) pre-end-P3, a0@P3(T-1) by LGKM(12) pre-end-P1.  (= r7 proofs)
#define HALF_ITER(BUF, OBUF, B0, B0N, T) do {                                      \
    /* P1: q00 = a0 x b0 */                                                        \
    READ_B(b1, BUF, 1);                                                            \
    READ_A(a1, BUF, 1);                                                            \
    LGKM(12);                                                                      \
    MFMA_Q(0, 0, a0, B0);                                                          \
    SBAR;                                                                          \
    /* P2: q01 = a0 x b1; stage B-half0(T+2); counted drain of T+1 */              \
    STAGE_H(BUF, 1, Bsrc, (T) + 2, 0);                                             \
    MFMA_Q(0, 1, a0, b1);                                                          \
    WAIT_VM(2);                                                                    \
    SBAR;                                                                          \
    /* P3: q11 = a1 x b1; stage B-half1(T+2); prefetch a0(T+1) */                  \
    STAGE_H(BUF, 1, Bsrc, (T) + 2, 1);                                             \
    READ_A(a0, OBUF, 0);                                                           \
    LGKM(8);                                                                       \
    MFMA_Q(1, 1, a1, b1);                                                          \
    SBAR;                                                                          \
    /* P4: q10 = a1 x b0; stage A(T+2); prefetch b0(T+1); no barrier */            \
    STAGE(BUF, 0, Asrc, (T) + 2);                                                  \
    READ_B(B0N, OBUF, 0);                                                          \
    MFMA_Q(1, 0, a1, B0);                                                          \
} while (0)

__global__ __launch_bounds__(512, 2) void gemm_i8(
    const signed char* __restrict__ A,   // [M, K] int8 (quantized x)
    const signed char* __restrict__ B,   // [N, K] int8 (weights)
    const float* __restrict__ sx,        // [M] row scales of x
    const float* __restrict__ scale,     // [N] channel scales of w
    float*       __restrict__ C)         // [M, N]
{
    __shared__ __align__(16) signed char lds[2][2][256 * 128];  // 128 KiB

    const int tid  = threadIdx.x;
    const int lane = tid & 63;
    const int fr   = lane & 15;
    const int fq   = lane >> 4;
    const int fr7  = fr & 7;
    const int wave = tid >> 6;
    const int mi   = wave >> 2;   // 0..1: A half (128-row block)
    const int ni   = wave & 3;    // 0..3: 64-col block

    // XCD-chunked bijective swizzle: 1376 = 8 x 172; per XCD: 4 bm x 43 bn.
    const int bid = blockIdx.x;
    const int xcd = bid & 7;
    const int idx = bid >> 3;
    const int bm  = xcd * 4 + (idx & 3);  // 0..31
    const int bn  = idx >> 2;             // 0..42

    // Pre-swizzled staging source: chunk c = i*512+tid -> row = i*64+(tid>>3),
    // src chunk = (tid&7) ^ (row&7) = (tid&7) ^ ((tid>>3)&7).  (bytes)
    const int jl   = (tid & 7) ^ ((tid >> 3) & 7);
    const int soff = (tid >> 3) * K_DIM + jl * 16;
    const signed char* Asrc = A + (size_t)bm * BM * K_DIM + soff;
    const signed char* Bsrc = B + (size_t)bn * BN * K_DIM + soff;

    i32x4 acc[8][4] = {};
    i32x4 a0[4][2], a1[4][2];            // A quadrants of current tile
    i32x4 b0e[2][2], b0o[2][2], b1[2][2];// b0 rotates per tile parity; b1 per-tile

    // Prologue: stage tiles 0,1; wait tile 0 landed (leave tile 1's 8 in
    // flight); pre-issue a0(T0), b0(T0) -> ledgers match steady state.
    STAGE(0, 1, Bsrc, 0);
    STAGE(0, 0, Asrc, 0);
    STAGE(1, 1, Bsrc, 1);
    STAGE(1, 0, Asrc, 1);
    WAIT_VM(8);
    SBAR;
    READ_A(a0, 0, 0);   // 8
    READ_B(b0e, 0, 0);  // 4  -> 12 outstanding = steady state
    for (int it = 0; it < 16; ++it) {
        const int t0 = 2 * it;
        HALF_ITER(0, 1, b0e, b0o, t0);      // tile t0   (buf0)
        HALF_ITER(1, 0, b0o, b0e, t0 + 1);  // tile t0+1 (buf1)
    }

    // Epilogue: per (i,jj) row, 4 consecutive jn-stores cover 256 B of the row.
    const int row0 = bm * BM + mi * 128 + fq * 4;
    const int col0 = bn * BN + ni * 64 + fr;
    float s4[4];
    #pragma unroll
    for (int jn = 0; jn < 4; ++jn) s4[jn] = scale[col0 + jn * 16];
    #pragma unroll
    for (int i = 0; i < 8; ++i) {
        #pragma unroll
        for (int jj = 0; jj < 4; ++jj) {
            const int r = row0 + i * 16 + jj;
            const float sxv = sx[r];
            #pragma unroll
            for (int jn = 0; jn < 4; ++jn)
                __builtin_nontemporal_store(
                    (float)acc[i][jn][jj] * sxv * s4[jn],
                    &C[(size_t)r * N_DIM + col0 + jn * 16]);
        }
    }
}

// ---- fallback (round-1 fused bf16 kernel) if ws is too small ----
#define FBM 128
#define FBN 128
#define FBK 32
#define LDK 40
__global__ __launch_bounds__(256) void int8_linear_fused(
    const float* __restrict__ A, const int* __restrict__ W,
    const float* __restrict__ scale, float* __restrict__ C)
{
    __shared__ short As[FBM][LDK];
    __shared__ short Bs[FBN][LDK];
    const int tid = threadIdx.x;
    const int bid = blockIdx.x;
    const int g   = bid / (8 * 86);
    const int rem = bid % (8 * 86);
    const int bm  = g * 8 + (rem & 7);
    const int bn  = rem >> 3;
    const int srow = tid >> 3;
    const int skq  = tid & 7;
    const float* Ab = A + (size_t)(bm * FBM + srow) * K_DIM + skq * 4;
    const int*   Wb = W + (size_t)(bn * FBN + srow) * K_DIM + skq * 4;
    const int lane = tid & 63, wave = tid >> 6;
    const int wm = (wave >> 1) * 64, wn = (wave & 1) * 64;
    const int fr = lane & 15, fq = lane >> 4;
    f32x4 acc[4][4] = {};
    f32x4 areg[4]; i32x4 breg[4];
    #pragma unroll
    for (int i = 0; i < 4; ++i) {
        areg[i] = *(const f32x4*)(Ab + (size_t)(i * 32) * K_DIM);
        breg[i] = *(const i32x4*)(Wb + (size_t)(i * 32) * K_DIM);
    }
    const int NT = K_DIM / FBK;
    for (int kt = 0; kt < NT; ++kt) {
        __syncthreads();
        #pragma unroll
        for (int i = 0; i < 4; ++i) {
            s16x4 av, bv;
            #pragma unroll
            for (int j = 0; j < 4; ++j) {
                av[j] = cvt_bf16(areg[i][j]);
                bv[j] = cvt_bf16((float)breg[i][j]);
            }
            *(s16x4*)&As[srow + i * 32][skq * 4] = av;
            *(s16x4*)&Bs[srow + i * 32][skq * 4] = bv;
        }
        __syncthreads();
        if (kt + 1 < NT) {
            const int k0 = (kt + 1) * FBK;
            #pragma unroll
            for (int i = 0; i < 4; ++i) {
                areg[i] = *(const f32x4*)(Ab + (size_t)(i * 32) * K_DIM + k0);
                breg[i] = *(const i32x4*)(Wb + (size_t)(i * 32) * K_DIM + k0);
            }
        }
        s16x8 af[4], bf[4];
        #pragma unroll
        for (int m = 0; m < 4; ++m) af[m] = *(const s16x8*)&As[wm + m * 16 + fr][fq * 8];
        #pragma unroll
        for (int n = 0; n < 4; ++n) bf[n] = *(const s16x8*)&Bs[wn + n * 16 + fr][fq * 8];
        #pragma unroll
        for (int m = 0; m < 4; ++m)
            #pragma unroll
            for (int n = 0; n < 4; ++n)
                acc[m][n] = __builtin_amdgcn_mfma_f32_16x16x32_bf16(af[m], bf[n], acc[m][n], 0, 0, 0);
    }
    #pragma unroll
    for (int n = 0; n < 4; ++n) {
        const int gn = bn * FBN + wn + n * 16 + fr;
        const float s = scale[gn];
        #pragma unroll
        for (int m = 0; m < 4; ++m) {
            const int gm0 = bm * FBM + wm + m * 16 + fq * 4;
            #pragma unroll
            for (int j = 0; j < 4; ++j)
                C[(size_t)(gm0 + j) * N_DIM + gn] = acc[m][n][j] * s;
        }
    }
}

extern "C" void kernel_launch(void* const* d_in, const int* in_sizes, int n_in,
                              void* d_out, int out_size, void* d_ws, size_t ws_size,
                              hipStream_t stream) {
    const float* x  = (const float*)d_in[0];
    const int*   w  = (const int*)d_in[1];
    const float* sc = (const float*)d_in[2];
    float* out = (float*)d_out;

    const size_t w_bytes  = (size_t)N_DIM * K_DIM;
    const size_t x_bytes  = (size_t)M_DIM * K_DIM;
    const size_t sx_bytes = (size_t)M_DIM * sizeof(float);
    const size_t need = w_bytes + x_bytes + sx_bytes;

    if (ws_size >= need) {
        signed char* qw = (signed char*)d_ws;
        signed char* qx = qw + w_bytes;
        float* sx = (float*)(qx + x_bytes);
        convert_w<<<dim3(2048), dim3(256), 0, stream>>>(w, qw, (int)(w_bytes / 16));
        quant_x<<<dim3(M_DIM), dim3(256), 0, stream>>>(x, qx, sx);
        const int nblocks = (M_DIM / BM) * (N_DIM / BN);  // 1376
        gemm_i8<<<dim3(nblocks), dim3(512), 0, stream>>>(qx, qw, sx, sc, out);
    } else {
        const int nblocks = (M_DIM / FBM) * (N_DIM / FBN);
        int8_linear_fused<<<dim3(nblocks), dim3(256), 0, stream>>>(x, w, sc, out);
    }
}